// Round 7
// baseline (274.993 us; speedup 1.0000x reference)
//
#include <hip/hip_runtime.h>
#include <hip/hip_fp16.h>

// LBP semantic dependency, channel-difference form, base-2 domain.
//   d'(x,p) = sp(x+p) - sp(x);  db[a,u] = edge + sum_{v!=a,u} sum_t d'-terms
// tp = e^p stored fp16, slice-major tq[t][n][a][v][u] (50KB contiguous slab
// per (n,a,t)). All db quantities in units of ln2.
// R7: (1) rcp-form inner loops: 2^(db - log2(1+t)) = E * rcp(1+t) with
//     E = 2^db precomputed per slice -> ph3 7->4, ph2 4->3 transcendentals.
// (2) pass1 atomicAdds phase-1 partials into db1 (P tensor deleted).
// (3) di2/di3 fused into ph2/ph3 (32 threads/block); k_mid only applies the
//     v==a / v==u exclusion correction db1r -> db1c (separate array: no race).

#define S    160
#define S2   25600            // 160*160
#define S3   4096000          // 160^3 (per-n slab, elements)
#define TSZ  8192000          // per tensor elements (2*160^3)
#define C2E  1.4426950408889634f

__device__ __forceinline__ float fexp2(float x) { return __builtin_amdgcn_exp2f(x); }
__device__ __forceinline__ float flog2(float x) { return __builtin_amdgcn_logf(x); }
__device__ __forceinline__ float frcp(float x)  { return __builtin_amdgcn_rcpf(x); }
__device__ __forceinline__ float cdb(float x) {
    return fminf(fmaxf(x, -100.f), 100.f);   // keeps exp2 finite; terms saturated anyway
}
__device__ __forceinline__ float sp2t(float tp) { return flog2(1.f + tp); }
__device__ __forceinline__ float Ff(float x, float tp) {
    float tx = fexp2(x);
    return flog2(1.f + tx * tp) - flog2(1.f + tx);
}
// tq element (v,u) of slice (n,a), tensor t:
#define TQ(tq, t, n, a, v, u) \
    (tq)[(long)(t) * TSZ + (long)(n) * S3 + (long)(a) * S2 + (v) * S + (u)]

// ---- db1 raw base: edge*C2E - 480 (the -1-per-(t,v) baseline, 3*160)
__global__ __launch_bounds__(256)
void k_init0(const float* __restrict__ s_edge, float* __restrict__ db1r) {
    int flat = blockIdx.x * 256 + threadIdx.x;
    int u = flat % S; int rest = flat / S; int a = rest % S; int n = rest / S;
    db1r[flat] = s_edge[n * S2 + u * S + a] * C2E - 480.f;
}

// ---- pass 1: sequential read s_t, write tq (slice-major fp16),
//      atomically accumulate sum_v sp2t into db1r
__global__ __launch_bounds__(640)
void k_pass1(const float* __restrict__ s_sib, const float* __restrict__ s_cop,
             const float* __restrict__ s_grd, __half* __restrict__ tq,
             float* __restrict__ db1r)
{
    int c = blockIdx.x;   // v-chunk of 4: 0..39
    int n = blockIdx.y;   // 0..1
    int t = blockIdx.z;   // 0..2
    const float* sT = (t == 0) ? s_sib : (t == 1) ? s_cop : s_grd;
    int tid = threadIdx.x;
    float4 acc[10];
    #pragma unroll
    for (int s = 0; s < 10; ++s) acc[s] = make_float4(0.f, 0.f, 0.f, 0.f);
    uint2* o2 = (uint2*)(tq + (long)t * TSZ + (long)n * S3);  // uint2 = 4 halves
    for (int vl = 0; vl < 4; ++vl) {
        int v = c * 4 + vl;
        const float4* g = (const float4*)(sT + (long)(n * S + v) * S2);
        #pragma unroll
        for (int s = 0; s < 10; ++s) {
            int idx = s * 640 + tid;            // (a, uq): a=idx/40, uq=idx%40
            float4 p = g[idx];
            float t0 = fexp2(p.x * C2E), t1 = fexp2(p.y * C2E);
            float t2 = fexp2(p.z * C2E), t3 = fexp2(p.w * C2E);
            acc[s].x += flog2(1.f + t0); acc[s].y += flog2(1.f + t1);
            acc[s].z += flog2(1.f + t2); acc[s].w += flog2(1.f + t3);
            __half2 h01 = __floats2half2_rn(t0, t1);
            __half2 h23 = __floats2half2_rn(t2, t3);
            uint2 w; w.x = *(unsigned*)&h01; w.y = *(unsigned*)&h23;
            int a = idx / 40, uq = idx - a * 40;
            o2[a * 6400 + v * 40 + uq] = w;     // tq[n][a][v][uq*4..]
        }
    }
    float* dst = db1r + n * S2;
    #pragma unroll
    for (int s = 0; s < 10; ++s) {
        int idx = s * 640 + tid;
        int a = idx / 40, uq = idx - a * 40;
        int base = a * S + uq * 4;
        atomicAdd(&dst[base],     acc[s].x);
        atomicAdd(&dst[base + 1], acc[s].y);
        atomicAdd(&dst[base + 2], acc[s].z);
        atomicAdd(&dst[base + 3], acc[s].w);
    }
}

// ---- apply exclusion correction: db1c = db1r - sum_t[(sp2t(tp(a,u))-1)
//      + (u!=a)(sp2t(tp(u,u))-1)]   (separate output array: no RAW race)
__global__ __launch_bounds__(256)
void k_mid(const __half* __restrict__ tq, const float* __restrict__ db1r,
           float* __restrict__ db1c)
{
    int flat = blockIdx.x * 256 + threadIdx.x;
    int u = flat % S; int rest = flat / S; int a = rest % S; int n = rest / S;
    float r = db1r[flat];
    for (int t = 0; t < 3; ++t) {
        float tpa = __half2float(TQ(tq, t, n, a, a, u));      // tp(v=a, u)
        r -= (sp2t(tpa) - 1.f);
        if (u != a) {
            float tpu = __half2float(TQ(tq, t, n, a, u, u));  // tp(u,u)
            r -= (sp2t(tpu) - 1.f);
        }
    }
    db1c[flat] = r;
}

// ---- phase 2 (+inline di2): db2[u] = di2[u] + sum_{t,v} F(db1[v]-sp2t(tp(u,v)), tp(v,u))
__global__ __launch_bounds__(256)
void k_ph2(const __half* __restrict__ tq, const float* __restrict__ db1c,
           const float* __restrict__ s_edge, float* __restrict__ db2)
{
    int bid = blockIdx.x;
    int slice = bid % 320;      // same-slice blocks -> same XCD (320 % 8 == 0)
    int q = bid / 320;
    int a = slice % S, n = slice / S;
    int u0 = q * 32;
    int tid = threadIdx.x;
    int uj = tid & 31, vs = tid >> 5;
    __shared__ __half A16[S * 32];      // tp(v, u in block)        (10 KB)
    __shared__ __half B16[32 * 164];    // tp(u in block, v), s=164 (10.5 KB)
    __shared__ float E1[S];             // 2^(db1[v]+1)
    __shared__ float accS[256];
    if (tid < S) E1[tid] = fexp2(cdb(db1c[slice * S + tid]) + 1.f);
    float di2r = 0.f;                   // inline di2 for u = u0+tid (tid<32)
    if (tid < 32) {
        int u = u0 + tid;
        float db1a1 = cdb(db1c[slice * S + a]) + 1.f;
        float db1u1 = cdb(db1c[slice * S + u]) + 1.f;
        float sum = 0.f;
        for (int t = 0; t < 3; ++t) {
            float tpa  = __half2float(TQ(tq, t, n, a, a, u));     // tp(v=a, u)
            float tpba = __half2float(TQ(tq, t, n, a, u, a));     // tp(u, v=a)
            sum += Ff(db1a1 - sp2t(tpba), tpa);                   // C2(v=a)
            if (u != a) {
                float tpu = __half2float(TQ(tq, t, n, a, u, u));
                sum += Ff(db1u1 - sp2t(tpu), tpu);                // C2(v=u)
            }
        }
        di2r = s_edge[n * S2 + u * S + a] * C2E - sum;
    }
    float acc = 0.f;
    const __half* slab0 = tq + (long)n * S3 + (long)a * S2;   // 50KB contiguous/t
    for (int t = 0; t < 3; ++t) {
        const __half* slab = slab0 + (long)t * TSZ;
        __syncthreads();
        for (int e = tid; e < 640; e += 256) {    // A: 160 rows x 4 half8 (64B/row)
            int row = e >> 2, c = e & 3;
            *(float4*)(&A16[e * 8]) = *(const float4*)(slab + row * S + u0 + c * 8);
        }
        for (int e = tid; e < 1280; e += 256) {   // B: rows u0..u0+31 = 10KB contiguous
            int r = e / 40, c = e - r * 40;
            *(uint2*)(&B16[r * 164 + c * 4]) = *(const uint2*)(slab + (u0 + r) * S + c * 4);
        }
        __syncthreads();
        #pragma unroll
        for (int k = 0; k < 20; ++k) {
            int vi = k * 8 + vs;
            float tA = __half2float(A16[k * 256 + tid]);
            float tB = __half2float(B16[uj * 164 + vi]);
            float e  = E1[vi] * frcp(1.f + tB);   // 2^(db1[v]+1 - sp2t(tB))
            acc += flog2(1.f + e * tA) - flog2(1.f + e);
        }
    }
    accS[tid] = acc; __syncthreads();
    if (tid < 32) {
        float s = di2r;
        #pragma unroll
        for (int j = 0; j < 8; ++j) s += accS[j * 32 + tid];
        db2[slice * S + u0 + tid] = s;
    }
}

// ---- phase 3 (+inline di3) + output
__global__ __launch_bounds__(256)
void k_ph3(const __half* __restrict__ tq, const float* __restrict__ db1c,
           const float* __restrict__ db2, const float* __restrict__ s_edge,
           float* __restrict__ outp)
{
    int bid = blockIdx.x;
    int slice = bid % 320;
    int q = bid / 320;
    int a = slice % S, n = slice / S;
    int u0 = q * 32;
    int tid = threadIdx.x;
    int uj = tid & 31, vs = tid >> 5;
    int ug = u0 + uj;
    __shared__ __half A16[S * 32];
    __shared__ __half B16[32 * 164];
    __shared__ float E2[S];             // 2^db2[v]
    __shared__ float accS[256];
    if (tid < S) E2[tid] = fexp2(cdb(db2[slice * S + tid]));
    float di3r = 0.f;                   // inline di3 for u = u0+tid (tid<32)
    if (tid < 32) {
        int u = u0 + tid;
        float db1u1 = cdb(db1c[slice * S + u]) + 1.f;
        float db2a = cdb(db2[slice * S + a]);
        float db2u = cdb(db2[slice * S + u]);
        float sum = 0.f;
        for (int t = 0; t < 3; ++t) {
            float tpa  = __half2float(TQ(tq, t, n, a, a, u));     // tp(v=a, u)
            float tpba = __half2float(TQ(tq, t, n, a, u, a));     // tp(u, v=a)
            float d2vu = Ff(db1u1 - sp2t(tpa), tpba);
            sum += Ff(db2a - d2vu, tpa);                          // C3(v=a)
            if (u != a) {
                float tpu = __half2float(TQ(tq, t, n, a, u, u));
                float d2  = Ff(db1u1 - sp2t(tpu), tpu);
                sum += Ff(db2u - d2, tpu);                        // C3(v=u)
            }
        }
        di3r = s_edge[n * S2 + u * S + a] * C2E - sum;
    }
    float E1u = fexp2(cdb(db1c[slice * S + ug]) + 1.f);   // 2^(db1[u]+1)
    float acc = 0.f;
    const __half* slab0 = tq + (long)n * S3 + (long)a * S2;
    for (int t = 0; t < 3; ++t) {
        const __half* slab = slab0 + (long)t * TSZ;
        __syncthreads();
        for (int e = tid; e < 640; e += 256) {
            int row = e >> 2, c = e & 3;
            *(float4*)(&A16[e * 8]) = *(const float4*)(slab + row * S + u0 + c * 8);
        }
        for (int e = tid; e < 1280; e += 256) {
            int r = e / 40, c = e - r * 40;
            *(uint2*)(&B16[r * 164 + c * 4]) = *(const uint2*)(slab + (u0 + r) * S + c * 4);
        }
        __syncthreads();
        #pragma unroll
        for (int k = 0; k < 20; ++k) {
            int vi = k * 8 + vs;
            float tA = __half2float(A16[k * 256 + tid]);   // tp(v,u)
            float tB = __half2float(B16[uj * 164 + vi]);   // tp(u,v)
            float rA = frcp(1.f + tA);
            float e2 = E1u * rA;                           // 2^(db1[u]+1-sp2t(tA))
            float w  = frcp(1.f + e2 * tB);
            float e3 = E2[vi] * ((1.f + e2) * w);          // 2^(db2[v]-d2[v,u])
            acc += flog2(1.f + e3 * tA) - flog2(1.f + e3); // d3[u,v]
        }
    }
    accS[tid] = acc; __syncthreads();
    if (tid < 32) {
        float s = di3r;
        #pragma unroll
        for (int j = 0; j < 8; ++j) s += accS[j * 32 + tid];
        float sc  = fminf(fmaxf(s, -60.f), 60.f);   // avoid exp2 overflow -> inf*0=NaN
        float tsg = fexp2(-sc);
        float r   = __fdividef(1.f, 1.f + tsg);
        long ob = ((long)(n * S + u0 + tid) * S + a) * 2;
        outp[ob]     = tsg * r;
        outp[ob + 1] = r;
    }
}

extern "C" void kernel_launch(void* const* d_in, const int* in_sizes, int n_in,
                              void* d_out, int out_size, void* d_ws, size_t ws_size,
                              hipStream_t stream) {
    const float* s_edge = (const float*)d_in[0];
    const float* s_sib  = (const float*)d_in[1];
    const float* s_cop  = (const float*)d_in[2];
    const float* s_grd  = (const float*)d_in[3];
    float* outp = (float*)d_out;

    __half* tq   = (__half*)d_ws;                            // 49,152,000 B
    float*  db1r = (float*)((char*)d_ws + 49152000);         // 51200 floats
    float*  db1c = db1r + 51200;
    float*  db2  = db1c + 51200;                             // total ~49.8 MB

    k_init0<<<200, 256, 0, stream>>>(s_edge, db1r);
    k_pass1<<<dim3(40, 2, 3), 640, 0, stream>>>(s_sib, s_cop, s_grd, tq, db1r);
    k_mid<<<200, 256, 0, stream>>>(tq, db1r, db1c);
    k_ph2<<<1600, 256, 0, stream>>>(tq, db1c, s_edge, db2);
    k_ph3<<<1600, 256, 0, stream>>>(tq, db1c, db2, s_edge, outp);
}

// Round 8
// 196.541 us; speedup vs baseline: 1.3992x; 1.3992x over previous
//
#include <hip/hip_runtime.h>
#include <hip/hip_fp16.h>

// LBP semantic dependency, channel-difference form, base-2 domain.
//   d'(x,p) = sp(x+p) - sp(x);  db[a,u] = edge + sum_{v!=a,u} sum_t d'-terms
// tp = e^p stored fp16, slice-major tq[t][n][a][v][u] (50KB contiguous slab
// per (n,a,t)). All db quantities in units of ln2.
// R8 = R6 pass1/reduce1 (register partials -> P tensor; R7's atomicAdd into
// db1 caused 120-way L2 contention: WRITE +71MB, pass1 46->130us)
//    + R7 ph2/ph3 (rcp-form inner loops, inline di2/di3).

#define S    160
#define S2   25600            // 160*160
#define S3   4096000          // 160^3 (per-n slab, elements)
#define TSZ  8192000          // per tensor elements (2*160^3)
#define C2E  1.4426950408889634f

__device__ __forceinline__ float fexp2(float x) { return __builtin_amdgcn_exp2f(x); }
__device__ __forceinline__ float flog2(float x) { return __builtin_amdgcn_logf(x); }
__device__ __forceinline__ float frcp(float x)  { return __builtin_amdgcn_rcpf(x); }
__device__ __forceinline__ float cdb(float x) {
    return fminf(fmaxf(x, -100.f), 100.f);   // keeps exp2 finite; terms saturated anyway
}
__device__ __forceinline__ float sp2t(float tp) { return flog2(1.f + tp); }
__device__ __forceinline__ float Ff(float x, float tp) {
    float tx = fexp2(x);
    return flog2(1.f + tx * tp) - flog2(1.f + tx);
}
// tq element (v,u) of slice (n,a), tensor t:
#define TQ(tq, t, n, a, v, u) \
    (tq)[(long)(t) * TSZ + (long)(n) * S3 + (long)(a) * S2 + (v) * S + (u)]

// ---- pass 1: sequential read s_t, write tq (slice-major fp16), fused ph1 partials
__global__ __launch_bounds__(640)
void k_pass1(const float* __restrict__ s_sib, const float* __restrict__ s_cop,
             const float* __restrict__ s_grd, __half* __restrict__ tq,
             float* __restrict__ P)
{
    int c = blockIdx.x;   // v-chunk of 4: 0..39
    int n = blockIdx.y;   // 0..1
    int t = blockIdx.z;   // 0..2
    const float* sT = (t == 0) ? s_sib : (t == 1) ? s_cop : s_grd;
    int tid = threadIdx.x;
    float4 acc[10];
    #pragma unroll
    for (int s = 0; s < 10; ++s) acc[s] = make_float4(0.f, 0.f, 0.f, 0.f);
    uint2* o2 = (uint2*)(tq + (long)t * TSZ + (long)n * S3);  // uint2 = 4 halves
    for (int vl = 0; vl < 4; ++vl) {
        int v = c * 4 + vl;
        const float4* g = (const float4*)(sT + (long)(n * S + v) * S2);
        #pragma unroll
        for (int s = 0; s < 10; ++s) {
            int idx = s * 640 + tid;            // (a, uq): a=idx/40, uq=idx%40
            float4 p = g[idx];
            float t0 = fexp2(p.x * C2E), t1 = fexp2(p.y * C2E);
            float t2 = fexp2(p.z * C2E), t3 = fexp2(p.w * C2E);
            acc[s].x += flog2(1.f + t0); acc[s].y += flog2(1.f + t1);
            acc[s].z += flog2(1.f + t2); acc[s].w += flog2(1.f + t3);
            __half2 h01 = __floats2half2_rn(t0, t1);
            __half2 h23 = __floats2half2_rn(t2, t3);
            uint2 w; w.x = *(unsigned*)&h01; w.y = *(unsigned*)&h23;
            int a = idx / 40, uq = idx - a * 40;
            o2[a * 6400 + v * 40 + uq] = w;     // tq[n][a][v][uq*4..]
        }
    }
    float4* Pf = (float4*)(P + (long)(t * 80 + c * 2 + n) * S2);
    #pragma unroll
    for (int s = 0; s < 10; ++s) Pf[s * 640 + tid] = acc[s];
}

// ---- reduce partials + edge + exclusion terms -> db1
__global__ __launch_bounds__(256)
void k_reduce1(const float* __restrict__ P, const float* __restrict__ s_edge,
               const __half* __restrict__ tq, float* __restrict__ db1)
{
    int flat = blockIdx.x * 256 + threadIdx.x;          // (n*S+a)*S+u
    int u = flat % S; int rest = flat / S; int a = rest % S; int n = rest / S;
    float s = 0.f;
    for (int t = 0; t < 3; ++t)
        for (int c = 0; c < 40; ++c)
            s += P[(long)(t * 80 + c * 2 + n) * S2 + a * S + u];
    float r = s_edge[n * S2 + u * S + a] * C2E + s - 480.f;   // -1 per (t,v): 3*160
    for (int t = 0; t < 3; ++t) {
        float tpa = __half2float(TQ(tq, t, n, a, a, u));      // tp(v=a, u)
        r -= (sp2t(tpa) - 1.f);
        if (u != a) {
            float tpu = __half2float(TQ(tq, t, n, a, u, u));  // tp(u,u)
            r -= (sp2t(tpu) - 1.f);
        }
    }
    db1[flat] = r;
}

// ---- phase 2 (+inline di2): db2[u] = di2[u] + sum_{t,v} F(db1[v]-sp2t(tp(u,v)), tp(v,u))
__global__ __launch_bounds__(256)
void k_ph2(const __half* __restrict__ tq, const float* __restrict__ db1c,
           const float* __restrict__ s_edge, float* __restrict__ db2)
{
    int bid = blockIdx.x;
    int slice = bid % 320;      // same-slice blocks -> same XCD (320 % 8 == 0)
    int q = bid / 320;
    int a = slice % S, n = slice / S;
    int u0 = q * 32;
    int tid = threadIdx.x;
    int uj = tid & 31, vs = tid >> 5;
    __shared__ __half A16[S * 32];      // tp(v, u in block)        (10 KB)
    __shared__ __half B16[32 * 164];    // tp(u in block, v), s=164 (10.5 KB)
    __shared__ float E1[S];             // 2^(db1[v]+1)
    __shared__ float accS[256];
    if (tid < S) E1[tid] = fexp2(cdb(db1c[slice * S + tid]) + 1.f);
    float di2r = 0.f;                   // inline di2 for u = u0+tid (tid<32)
    if (tid < 32) {
        int u = u0 + tid;
        float db1a1 = cdb(db1c[slice * S + a]) + 1.f;
        float db1u1 = cdb(db1c[slice * S + u]) + 1.f;
        float sum = 0.f;
        for (int t = 0; t < 3; ++t) {
            float tpa  = __half2float(TQ(tq, t, n, a, a, u));     // tp(v=a, u)
            float tpba = __half2float(TQ(tq, t, n, a, u, a));     // tp(u, v=a)
            sum += Ff(db1a1 - sp2t(tpba), tpa);                   // C2(v=a)
            if (u != a) {
                float tpu = __half2float(TQ(tq, t, n, a, u, u));
                sum += Ff(db1u1 - sp2t(tpu), tpu);                // C2(v=u)
            }
        }
        di2r = s_edge[n * S2 + u * S + a] * C2E - sum;
    }
    float acc = 0.f;
    const __half* slab0 = tq + (long)n * S3 + (long)a * S2;   // 50KB contiguous/t
    for (int t = 0; t < 3; ++t) {
        const __half* slab = slab0 + (long)t * TSZ;
        __syncthreads();
        for (int e = tid; e < 640; e += 256) {    // A: 160 rows x 4 half8 (64B/row)
            int row = e >> 2, c = e & 3;
            *(float4*)(&A16[e * 8]) = *(const float4*)(slab + row * S + u0 + c * 8);
        }
        for (int e = tid; e < 1280; e += 256) {   // B: rows u0..u0+31 = 10KB contiguous
            int r = e / 40, c = e - r * 40;
            *(uint2*)(&B16[r * 164 + c * 4]) = *(const uint2*)(slab + (u0 + r) * S + c * 4);
        }
        __syncthreads();
        #pragma unroll
        for (int k = 0; k < 20; ++k) {
            int vi = k * 8 + vs;
            float tA = __half2float(A16[k * 256 + tid]);
            float tB = __half2float(B16[uj * 164 + vi]);
            float e  = E1[vi] * frcp(1.f + tB);   // 2^(db1[v]+1 - sp2t(tB))
            acc += flog2(1.f + e * tA) - flog2(1.f + e);
        }
    }
    accS[tid] = acc; __syncthreads();
    if (tid < 32) {
        float s = di2r;
        #pragma unroll
        for (int j = 0; j < 8; ++j) s += accS[j * 32 + tid];
        db2[slice * S + u0 + tid] = s;
    }
}

// ---- phase 3 (+inline di3) + output
__global__ __launch_bounds__(256)
void k_ph3(const __half* __restrict__ tq, const float* __restrict__ db1c,
           const float* __restrict__ db2, const float* __restrict__ s_edge,
           float* __restrict__ outp)
{
    int bid = blockIdx.x;
    int slice = bid % 320;
    int q = bid / 320;
    int a = slice % S, n = slice / S;
    int u0 = q * 32;
    int tid = threadIdx.x;
    int uj = tid & 31, vs = tid >> 5;
    int ug = u0 + uj;
    __shared__ __half A16[S * 32];
    __shared__ __half B16[32 * 164];
    __shared__ float E2[S];             // 2^db2[v]
    __shared__ float accS[256];
    if (tid < S) E2[tid] = fexp2(cdb(db2[slice * S + tid]));
    float di3r = 0.f;                   // inline di3 for u = u0+tid (tid<32)
    if (tid < 32) {
        int u = u0 + tid;
        float db1u1 = cdb(db1c[slice * S + u]) + 1.f;
        float db2a = cdb(db2[slice * S + a]);
        float db2u = cdb(db2[slice * S + u]);
        float sum = 0.f;
        for (int t = 0; t < 3; ++t) {
            float tpa  = __half2float(TQ(tq, t, n, a, a, u));     // tp(v=a, u)
            float tpba = __half2float(TQ(tq, t, n, a, u, a));     // tp(u, v=a)
            float d2vu = Ff(db1u1 - sp2t(tpa), tpba);
            sum += Ff(db2a - d2vu, tpa);                          // C3(v=a)
            if (u != a) {
                float tpu = __half2float(TQ(tq, t, n, a, u, u));
                float d2  = Ff(db1u1 - sp2t(tpu), tpu);
                sum += Ff(db2u - d2, tpu);                        // C3(v=u)
            }
        }
        di3r = s_edge[n * S2 + u * S + a] * C2E - sum;
    }
    float E1u = fexp2(cdb(db1c[slice * S + ug]) + 1.f);   // 2^(db1[u]+1)
    float acc = 0.f;
    const __half* slab0 = tq + (long)n * S3 + (long)a * S2;
    for (int t = 0; t < 3; ++t) {
        const __half* slab = slab0 + (long)t * TSZ;
        __syncthreads();
        for (int e = tid; e < 640; e += 256) {
            int row = e >> 2, c = e & 3;
            *(float4*)(&A16[e * 8]) = *(const float4*)(slab + row * S + u0 + c * 8);
        }
        for (int e = tid; e < 1280; e += 256) {
            int r = e / 40, c = e - r * 40;
            *(uint2*)(&B16[r * 164 + c * 4]) = *(const uint2*)(slab + (u0 + r) * S + c * 4);
        }
        __syncthreads();
        #pragma unroll
        for (int k = 0; k < 20; ++k) {
            int vi = k * 8 + vs;
            float tA = __half2float(A16[k * 256 + tid]);   // tp(v,u)
            float tB = __half2float(B16[uj * 164 + vi]);   // tp(u,v)
            float rA = frcp(1.f + tA);
            float e2 = E1u * rA;                           // 2^(db1[u]+1-sp2t(tA))
            float w  = frcp(1.f + e2 * tB);
            float e3 = E2[vi] * ((1.f + e2) * w);          // 2^(db2[v]-d2[v,u])
            acc += flog2(1.f + e3 * tA) - flog2(1.f + e3); // d3[u,v]
        }
    }
    accS[tid] = acc; __syncthreads();
    if (tid < 32) {
        float s = di3r;
        #pragma unroll
        for (int j = 0; j < 8; ++j) s += accS[j * 32 + tid];
        float sc  = fminf(fmaxf(s, -60.f), 60.f);   // avoid exp2 overflow -> inf*0=NaN
        float tsg = fexp2(-sc);
        float r   = __fdividef(1.f, 1.f + tsg);
        long ob = ((long)(n * S + u0 + tid) * S + a) * 2;
        outp[ob]     = tsg * r;
        outp[ob + 1] = r;
    }
}

extern "C" void kernel_launch(void* const* d_in, const int* in_sizes, int n_in,
                              void* d_out, int out_size, void* d_ws, size_t ws_size,
                              hipStream_t stream) {
    const float* s_edge = (const float*)d_in[0];
    const float* s_sib  = (const float*)d_in[1];
    const float* s_cop  = (const float*)d_in[2];
    const float* s_grd  = (const float*)d_in[3];
    float* outp = (float*)d_out;

    __half* tq  = (__half*)d_ws;                             // 49,152,000 B
    float*  P   = (float*)((char*)d_ws + 49152000);          // 24,576,000 B
    float*  db1 = P + 6144000;
    float*  db2 = db1 + 51200;                               // total ~74.1 MB

    k_pass1<<<dim3(40, 2, 3), 640, 0, stream>>>(s_sib, s_cop, s_grd, tq, P);
    k_reduce1<<<200, 256, 0, stream>>>(P, s_edge, tq, db1);
    k_ph2<<<1600, 256, 0, stream>>>(tq, db1, s_edge, db2);
    k_ph3<<<1600, 256, 0, stream>>>(tq, db1, db2, s_edge, outp);
}